// Round 2
// baseline (5695.317 us; speedup 1.0000x reference)
//
#include <hip/hip_runtime.h>
#include <hip/hip_bf16.h>

// SubQAttention: B=4, H=16, T=1024, D=64, N_BINS=16, ROUTER_HIDDEN=128
// Stage 1: router_kernel  -> bucket_probs [B*T, 16]   (fp32, in ws)
// Stage 2: mask_kernel    -> causal&bucket bitmask [B*T, 16] uint64 (in ws)
// Stage 3: attn_v2        -> flash attention, lane=q-row, K/V via SGPR,
//                            zero LDS in inner loop, 4-wave key split + merge

#define B_ 4
#define H_ 16
#define T_ 1024
#define D_ 64
#define NB 16
#define RH 128

// ---------------- Stage 1: router (8 rows per block, 256 threads) ----------
__global__ __launch_bounds__(256) void router_kernel(
    const float* __restrict__ kin, const float* __restrict__ W1,
    const float* __restrict__ b1, const float* __restrict__ W2,
    const float* __restrict__ b2, float* __restrict__ probs) {
  __shared__ float rows[8][1024];
  __shared__ float part[8][2][RH];
  __shared__ float hid[8][RH + 1];
  __shared__ float logits[8][NB];

  const int tid = threadIdx.x;
  const int half = tid >> 7;
  const int hu = tid & 127;
  const int bb = blockIdx.x;
  const int b = bb >> 7;
  const int t0 = (bb & 127) << 3;

  for (int idx = tid; idx < 8 * 1024; idx += 256) {
    const int r = idx >> 10, i = idx & 1023;
    rows[r][i] = kin[(((size_t)(b * H_) + (i >> 6)) * T_ + (t0 + r)) * D_ + (i & 63)];
  }
  __syncthreads();

  float acc[8];
#pragma unroll
  for (int r = 0; r < 8; r++) acc[r] = 0.0f;
  const int ib = half << 9;
  for (int i0 = 0; i0 < 512; i0 += 8) {
#pragma unroll
    for (int u = 0; u < 8; u++) {
      const float w = W1[(size_t)(ib + i0 + u) * RH + hu];
#pragma unroll
      for (int r = 0; r < 8; r++) acc[r] += rows[r][ib + i0 + u] * w;
    }
  }
#pragma unroll
  for (int r = 0; r < 8; r++) part[r][half][hu] = acc[r];
  __syncthreads();

  if (half == 0) {
#pragma unroll
    for (int r = 0; r < 8; r++)
      hid[r][hu] = tanhf(part[r][0][hu] + part[r][1][hu] + b1[hu]);
  }
  __syncthreads();

  if (tid < 128) {
    const int r = tid >> 4, bin = tid & 15;
    float a = b2[bin];
#pragma unroll
    for (int jj = 0; jj < RH; jj++) a += hid[r][jj] * W2[jj * NB + bin];
    logits[r][bin] = a;
  }
  __syncthreads();

  if (tid < 8) {
    const int r = tid;
    float mx = -INFINITY;
#pragma unroll
    for (int bin = 0; bin < NB; bin++) mx = fmaxf(mx, logits[r][bin]);
    float e[NB];
    float s = 0.0f;
#pragma unroll
    for (int bin = 0; bin < NB; bin++) {
      e[bin] = expf(logits[r][bin] - mx);
      s += e[bin];
    }
    const float inv = 1.0f / s;
    const size_t row = (size_t)(b * T_ + t0 + r) * NB;
#pragma unroll
    for (int bin = 0; bin < NB; bin++) probs[row + bin] = e[bin] * inv;
  }
}

// ---------------- Stage 2: bucket bitmask (one block per (b,i) row) --------
__global__ __launch_bounds__(256) void mask_kernel(
    const float* __restrict__ probs, unsigned long long* __restrict__ mask) {
  const int blk = blockIdx.x;  // b*T + i
  const int b = blk >> 10;
  const int i = blk & 1023;
  const int tid = threadIdx.x;

  float pi[NB];
#pragma unroll
  for (int kk = 0; kk < NB; kk++) pi[kk] = probs[(size_t)blk * NB + kk];

#pragma unroll
  for (int c = 0; c < 4; c++) {
    const int j = c * 256 + tid;
    const float* pj = probs + ((size_t)(b << 10) + j) * NB;
    float sim = 0.0f;
#pragma unroll
    for (int kk = 0; kk < NB; kk++) sim += pi[kk] * pj[kk];
    const bool ok = (j <= i) && (sim > 0.05f);
    const unsigned long long bal = __ballot(ok);
    if ((tid & 63) == 0)
      mask[((size_t)blk << 4) + (c * 4 + (tid >> 6))] = bal;
  }
}

// ---------------- Stage 3: attention, v2 -----------------------------------
// Block = 4 waves, handles (bh, q-tile of 64 rows). lane = q-row.
// Q[64] and O[64] in VGPRs. K/V addresses are wave-uniform -> compiler
// scalarizes to s_load; inner loops are pure v_fmac (s,v) with ZERO LDS ops.
// Wave w processes key-words t = w, w+4, ...; flash-merge of 4 partials at end.
// Mask word includes causality; diagonal always passes (||p||^2 >= 1/16 > 0.05)
// so the merged running max is always finite.
__global__ __launch_bounds__(256, 3) void attn_v2(
    const float* __restrict__ q, const float* __restrict__ k,
    const float* __restrict__ v, const unsigned long long* __restrict__ mask,
    float* __restrict__ out) {
  __shared__ float Opart[3][64][64];   // waves 1..3 partial O, f4-swizzled
  __shared__ float mpart[4][64];
  __shared__ float lpart[4][64];

  const int bh = blockIdx.x;           // b*H + h
  const int qt = blockIdx.y;           // q tile 0..15
  const int b = bh >> 4;
  const int wave = threadIdx.x >> 6;
  const int lane = threadIdx.x & 63;
  const size_t base = (size_t)bh * (T_ * D_);
  const int row = qt * 64 + lane;      // this lane's q row

  // Q row -> 64 VGPRs (per-lane contiguous 256B, one time)
  float Q[64];
  {
    const float* qp = q + base + (size_t)row * D_;
#pragma unroll
    for (int d4 = 0; d4 < 16; d4++) {
      const float4 f = *(const float4*)(qp + d4 * 4);
      Q[d4 * 4 + 0] = f.x; Q[d4 * 4 + 1] = f.y;
      Q[d4 * 4 + 2] = f.z; Q[d4 * 4 + 3] = f.w;
    }
  }

  float O[64];
#pragma unroll
  for (int d = 0; d < 64; d++) O[d] = 0.0f;
  float mrun = -INFINITY, lrun = 0.0f;

  const int W = qt + 1;  // number of 64-key words
  const unsigned long long* mrow = mask + ((size_t)(b * T_ + row) << 4);

  for (int t = wave; t < W; t += 4) {
    const unsigned long long mw = mrow[t];          // per-lane (per-row) mask
    if (!__any(mw != 0ull)) continue;               // word dead for all rows

    const float* kw = k + base + (size_t)t * (64 * D_);  // uniform
    const float* vw = v + base + (size_t)t * (64 * D_);  // uniform

#pragma unroll 1
    for (int g = 0; g < 4; g++) {                   // 16-key groups
      // ---- scores (uniform K -> s_load; pure v_fmac)
      float S[16];
#pragma unroll
      for (int j = 0; j < 16; j++) {
        const float* kr = kw + (size_t)(g * 16 + j) * D_;
        float acc = 0.0f;
#pragma unroll
        for (int d = 0; d < 64; d++) acc += kr[d] * Q[d];
        S[j] = acc;
      }

      // ---- mask + group max
      float gmax = -INFINITY;
#pragma unroll
      for (int j = 0; j < 16; j++) {
        const bool ok = (mw >> (g * 16 + j)) & 1ull;
        S[j] = ok ? S[j] * 0.125f : -INFINITY;      // scale = D^-0.5
        gmax = fmaxf(gmax, S[j]);
      }

      // ---- deferred rescale (T13, THR=8): rare wave-uniform branch
      if (__any(gmax > mrun + 8.0f)) {
        const float mnew = fmaxf(mrun, gmax);
        // mnew==-inf => this lane fully masked so far: corr=1, O stays 0
        const float corr = (mnew == -INFINITY) ? 1.0f : __expf(mrun - mnew);
        lrun *= corr;
#pragma unroll
        for (int d = 0; d < 64; d++) O[d] *= corr;
        mrun = mnew;
      }

      // ---- p = exp(S - m), l += p, O += p * V   (uniform V -> s_load)
      float lsum = 0.0f;
#pragma unroll
      for (int j = 0; j < 16; j++) {
        const int jj = g * 16 + j;
        // masked j have S=-inf; mrun finite whenever any S finite
        const float p = ((mw >> jj) & 1ull) ? __expf(S[j] - mrun) : 0.0f;
        lsum += p;
        const float* vr = vw + (size_t)jj * D_;
#pragma unroll
        for (int d = 0; d < 64; d++) O[d] += p * vr[d];
      }
      lrun += lsum;
    }
  }

  // ---- cross-wave flash merge (one time)
  if (wave != 0) {
#pragma unroll
    for (int d4 = 0; d4 < 16; d4++) {
      float4 o4;
      o4.x = O[d4 * 4 + 0]; o4.y = O[d4 * 4 + 1];
      o4.z = O[d4 * 4 + 2]; o4.w = O[d4 * 4 + 3];
      *(float4*)&Opart[wave - 1][lane][(d4 ^ (lane & 15)) * 4] = o4;  // swizzled
    }
  }
  mpart[wave][lane] = mrun;
  lpart[wave][lane] = lrun;
  __syncthreads();

  if (wave == 0) {
    float mstar = mrun;
#pragma unroll
    for (int w = 1; w < 4; w++) mstar = fmaxf(mstar, mpart[w][lane]);
    float wt[4];
    float ltot = 0.0f;
#pragma unroll
    for (int w = 0; w < 4; w++) {
      const float mw_ = mpart[w][lane];
      wt[w] = (mw_ == -INFINITY) ? 0.0f : __expf(mw_ - mstar);
      ltot += wt[w] * lpart[w][lane];
    }
    const float inv = 1.0f / ltot;
    float* op = out + base + (size_t)row * D_;
#pragma unroll
    for (int d4 = 0; d4 < 16; d4++) {
      float4 o4;
#pragma unroll
      for (int dd = 0; dd < 4; dd++) {
        const int d = d4 * 4 + dd;
        float acc = wt[0] * O[d];
#pragma unroll
        for (int w = 1; w < 4; w++)
          acc += wt[w] * Opart[w - 1][lane][(d4 ^ (lane & 15)) * 4 + dd];
        (&o4.x)[dd] = acc * inv;
      }
      *(float4*)(op + d4 * 4) = o4;
    }
  }
}

extern "C" void kernel_launch(void* const* d_in, const int* in_sizes, int n_in,
                              void* d_out, int out_size, void* d_ws, size_t ws_size,
                              hipStream_t stream) {
  const float* q  = (const float*)d_in[0];
  const float* k  = (const float*)d_in[1];
  const float* v  = (const float*)d_in[2];
  const float* W1 = (const float*)d_in[3];
  const float* b1 = (const float*)d_in[4];
  const float* W2 = (const float*)d_in[5];
  const float* b2 = (const float*)d_in[6];
  float* out = (float*)d_out;

  // ws layout: probs [B*T*16] f32 (256 KB) | mask [B*T*16] u64 (512 KB)
  float* probs = (float*)d_ws;
  unsigned long long* mask =
      (unsigned long long*)((char*)d_ws + (size_t)B_ * T_ * NB * sizeof(float));

  router_kernel<<<512, 256, 0, stream>>>(k, W1, b1, W2, b2, probs);
  mask_kernel<<<B_ * T_, 256, 0, stream>>>(probs, mask);
  attn_v2<<<dim3(B_ * H_, T_ / 64), 256, 0, stream>>>(q, k, v, mask, out);
}

// Round 8
// 226.450 us; speedup vs baseline: 25.1504x; 25.1504x over previous
//
#include <hip/hip_runtime.h>
#include <hip/hip_bf16.h>

// SubQAttention: B=4, H=16, T=1024, D=64, N_BINS=16, ROUTER_HIDDEN=128
// Stage 1: router_kernel -> bucket_probs [B*T,16] f32 (ws)
// Stage 2: mask_v2       -> causal&bucket bitmask [B*T,16] u64 (ws)
// Stage 3: attn_mfma     -> flash attention via split-bf16 MFMA (3-term
//          Markidis: Ah*Bh + Ah*Bl + Al*Bh ~ fp32 accuracy) on 16x16x32.
//          Swapped QK^T (mfma(K,Q)) -> per-lane softmax rows, no shuffles
//          in the hot path. All LDS tiles XOR-swizzled (byte ^= (row&7)<<4).

#define B_ 4
#define H_ 16
#define T_ 1024
#define D_ 64
#define NB 16
#define RH 128

typedef __attribute__((ext_vector_type(8))) short s16x8;
typedef __attribute__((ext_vector_type(4))) float f32x4;

__device__ __forceinline__ unsigned short f2bf(float x) {  // RTN f32->bf16
  unsigned u = __float_as_uint(x);
  u = (u + 0x7fffu + ((u >> 16) & 1u)) >> 16;
  return (unsigned short)u;
}
__device__ __forceinline__ float bf2f(unsigned short h) {
  return __uint_as_float(((unsigned)h) << 16);
}

// ---------------- Stage 1: router (unchanged, validated) -------------------
__global__ __launch_bounds__(256) void router_kernel(
    const float* __restrict__ kin, const float* __restrict__ W1,
    const float* __restrict__ b1, const float* __restrict__ W2,
    const float* __restrict__ b2, float* __restrict__ probs) {
  __shared__ float rows[8][1024];
  __shared__ float part[8][2][RH];
  __shared__ float hid[8][RH + 1];
  __shared__ float logits[8][NB];

  const int tid = threadIdx.x;
  const int half = tid >> 7;
  const int hu = tid & 127;
  const int bb = blockIdx.x;
  const int b = bb >> 7;
  const int t0 = (bb & 127) << 3;

  for (int idx = tid; idx < 8 * 1024; idx += 256) {
    const int r = idx >> 10, i = idx & 1023;
    rows[r][i] = kin[(((size_t)(b * H_) + (i >> 6)) * T_ + (t0 + r)) * D_ + (i & 63)];
  }
  __syncthreads();

  float acc[8];
#pragma unroll
  for (int r = 0; r < 8; r++) acc[r] = 0.0f;
  const int ib = half << 9;
  for (int i0 = 0; i0 < 512; i0 += 8) {
#pragma unroll
    for (int u = 0; u < 8; u++) {
      const float w = W1[(size_t)(ib + i0 + u) * RH + hu];
#pragma unroll
      for (int r = 0; r < 8; r++) acc[r] += rows[r][ib + i0 + u] * w;
    }
  }
#pragma unroll
  for (int r = 0; r < 8; r++) part[r][half][hu] = acc[r];
  __syncthreads();

  if (half == 0) {
#pragma unroll
    for (int r = 0; r < 8; r++)
      hid[r][hu] = tanhf(part[r][0][hu] + part[r][1][hu] + b1[hu]);
  }
  __syncthreads();

  if (tid < 128) {
    const int r = tid >> 4, bin = tid & 15;
    float a = b2[bin];
#pragma unroll
    for (int jj = 0; jj < RH; jj++) a += hid[r][jj] * W2[jj * NB + bin];
    logits[r][bin] = a;
  }
  __syncthreads();

  if (tid < 8) {
    const int r = tid;
    float mx = -INFINITY;
#pragma unroll
    for (int bin = 0; bin < NB; bin++) mx = fmaxf(mx, logits[r][bin]);
    float e[NB];
    float s = 0.0f;
#pragma unroll
    for (int bin = 0; bin < NB; bin++) {
      e[bin] = expf(logits[r][bin] - mx);
      s += e[bin];
    }
    const float inv = 1.0f / s;
    const size_t row = (size_t)(b * T_ + t0 + r) * NB;
#pragma unroll
    for (int bin = 0; bin < NB; bin++) probs[row + bin] = e[bin] * inv;
  }
}

// ---------------- Stage 2: bitmask, 64 blocks, pj-in-regs ------------------
__global__ __launch_bounds__(256) void mask_v2(
    const float* __restrict__ probs, unsigned long long* __restrict__ mask) {
  __shared__ float P[1024][NB];  // 64 KB: whole batch's probs
  const int blk = blockIdx.x, b = blk >> 4, i0 = (blk & 15) * 64;
  const int tid = threadIdx.x, w = tid >> 6, lane = tid & 63;
  const float* src = probs + (size_t)b * (T_ * NB);
#pragma unroll
  for (int i4 = 0; i4 < 16; i4++)
    ((float4*)P)[tid + 256 * i4] = ((const float4*)src)[tid + 256 * i4];
  __syncthreads();

#pragma unroll
  for (int jc = 0; jc < 4; jc++) {
    const int j = jc * 256 + w * 64 + lane;  // wave = 64 consecutive j
    float pj[NB];
#pragma unroll
    for (int kk = 0; kk < NB; kk++) pj[kk] = P[j][kk];
    for (int ii = 0; ii < 64; ii++) {
      const int i = i0 + ii;
      float sim = 0.f;
#pragma unroll
      for (int kk = 0; kk < NB; kk++) sim += P[i][kk] * pj[kk];  // pi bcast
      const unsigned long long bal = __ballot((j <= i) && (sim > 0.05f));
      if (lane == 0) mask[((size_t)(b * T_ + i) << 4) + jc * 4 + w] = bal;
    }
  }
}

// ---------------- Stage 3: split-bf16 MFMA flash attention -----------------
// Block = 4 waves, (bh, q-tile of 64). Wave w owns q-rows w*16..+15.
// Swapped QK^T: S^T = K_tile . Q^T -> lane's softmax row = lane&15.
// 3-term split everywhere keeps fp32 accuracy.
__global__ __launch_bounds__(256, 2) void attn_mfma(
    const float* __restrict__ q, const float* __restrict__ k,
    const float* __restrict__ v, const unsigned long long* __restrict__ mask,
    float* __restrict__ out) {
  __shared__ unsigned short Kh[64 * 64], Kl[64 * 64];    // [key][d]  swz
  __shared__ unsigned short Vth[64 * 64], Vtl[64 * 64];  // [d][key]  swz
  __shared__ unsigned short Phs[4][1024], Pls[4][1024];  // per-wave [qrow][key] swz

  const int bh = blockIdx.x, qt = blockIdx.y;
  const int b = bh >> 4;
  const int tid = threadIdx.x, w = tid >> 6, lane = tid & 63;
  const int lr = lane & 15;   // qrow-local / d-local (MFMA 16-field)
  const int g = lane >> 4;    // k-group (MFMA 4-field)
  const size_t base = (size_t)bh * (T_ * D_);
  const int qrow_g = qt * 64 + w * 16 + lr;
  const unsigned swz = ((unsigned)(lr & 7)) << 4;

  // ---- Q fragments (pre-scaled by D^-0.5 = 0.125, split hi/lo) ----
  s16x8 qfh[2], qfl[2];
  {
    const float* qp = q + base + (size_t)qrow_g * D_;
#pragma unroll
    for (int ks = 0; ks < 2; ks++) {
      union { unsigned short us[8]; s16x8 v; } h, l;
#pragma unroll
      for (int e2 = 0; e2 < 2; e2++) {
        const float4 f = *(const float4*)(qp + 32 * ks + 8 * g + 4 * e2);
#pragma unroll
        for (int e = 0; e < 4; e++) {
          const float x = (&f.x)[e] * 0.125f;
          const unsigned short hh = f2bf(x);
          h.us[4 * e2 + e] = hh;
          l.us[4 * e2 + e] = f2bf(x - bf2f(hh));
        }
      }
      qfh[ks] = h.v; qfl[ks] = l.v;
    }
  }

  f32x4 Oacc[4];
#pragma unroll
  for (int n = 0; n < 4; n++) Oacc[n] = (f32x4){0.f, 0.f, 0.f, 0.f};
  float mrun = -INFINITY, lrun = 0.f;

  const unsigned long long* mrow = mask + ((size_t)(b * T_ + qrow_g) << 4);
  const int dv = tid & 63, k0v = (tid >> 6) * 16;  // V-stage mapping

  // ---- prologue: load tile 0 into regs ----
  float Kst[16], Vst[16], Kst2[16], Vst2[16];
  {
    const float4* kp4 = (const float4*)(k + base);
    const float* vp = v + base;
#pragma unroll
    for (int i = 0; i < 4; i++) {
      const float4 f = kp4[tid + 256 * i];
      Kst[4 * i + 0] = f.x; Kst[4 * i + 1] = f.y;
      Kst[4 * i + 2] = f.z; Kst[4 * i + 3] = f.w;
    }
#pragma unroll
    for (int j = 0; j < 16; j++) Vst[j] = vp[(size_t)(k0v + j) * D_ + dv];
  }
  unsigned long long mw = mrow[0];

  for (int kt = 0; kt <= qt; kt++) {
    __syncthreads();  // previous tile's LDS reads done (barrier drains lgkm)
    // ---- write stage: cvt + split + swizzled LDS writes ----
#pragma unroll
    for (int i = 0; i < 4; i++) {  // K: [key][d], b64 per float4
      const int flat4 = tid + 256 * i, key = flat4 >> 4, dq = flat4 & 15;
      union { unsigned short us[4]; uint2 d; } h, l;
#pragma unroll
      for (int e = 0; e < 4; e++) {
        const float x = Kst[4 * i + e];
        const unsigned short hh = f2bf(x);
        h.us[e] = hh; l.us[e] = f2bf(x - bf2f(hh));
      }
      const unsigned byte = (unsigned)(key * 128 + dq * 8) ^ (((unsigned)(key & 7)) << 4);
      *(uint2*)((char*)Kh + byte) = h.d;
      *(uint2*)((char*)Kl + byte) = l.d;
    }
#pragma unroll
    for (int i = 0; i < 2; i++) {  // V transposed: [d][key], b128 per 8 keys
      union { unsigned short us[8]; uint4 q; } h, l;
#pragma unroll
      for (int j = 0; j < 8; j++) {
        const float x = Vst[8 * i + j];
        const unsigned short hh = f2bf(x);
        h.us[j] = hh; l.us[j] = f2bf(x - bf2f(hh));
      }
      const unsigned byte =
          (unsigned)(dv * 128 + (k0v + 8 * i) * 2) ^ (((unsigned)(dv & 7)) << 4);
      *(uint4*)((char*)Vth + byte) = h.q;
      *(uint4*)((char*)Vtl + byte) = l.q;
    }
    __syncthreads();  // staged tile visible

    // ---- prefetch next tile (hidden under compute) ----
    const int ktn = (kt < qt) ? kt + 1 : qt;
    {
      const float4* kp4 = (const float4*)(k + base + (size_t)(ktn * 64) * D_);
      const float* vp = v + base + (size_t)(ktn * 64) * D_;
#pragma unroll
      for (int i = 0; i < 4; i++) {
        const float4 f = kp4[tid + 256 * i];
        Kst2[4 * i + 0] = f.x; Kst2[4 * i + 1] = f.y;
        Kst2[4 * i + 2] = f.z; Kst2[4 * i + 3] = f.w;
      }
#pragma unroll
      for (int j = 0; j < 16; j++) Vst2[j] = vp[(size_t)(k0v + j) * D_ + dv];
    }
    const unsigned long long mwn = mrow[ktn];

    if (__any(mw != 0ull)) {
      // ---- QK^T (swapped): S4[m][r] = S[key=16m+4g+r][qrow=lr], pre-scaled
      f32x4 S4[4];
#pragma unroll
      for (int m = 0; m < 4; m++) {
        f32x4 acc = (f32x4){0.f, 0.f, 0.f, 0.f};
#pragma unroll
        for (int ks = 0; ks < 2; ks++) {
          const unsigned byte =
              ((unsigned)((16 * m + lr) * 128 + 64 * ks + 16 * g)) ^ swz;
          const s16x8 kfh = *(const s16x8*)((const char*)Kh + byte);
          const s16x8 kfl = *(const s16x8*)((const char*)Kl + byte);
          acc = __builtin_amdgcn_mfma_f32_16x16x32_bf16(kfh, qfh[ks], acc, 0, 0, 0);
          acc = __builtin_amdgcn_mfma_f32_16x16x32_bf16(kfh, qfl[ks], acc, 0, 0, 0);
          acc = __builtin_amdgcn_mfma_f32_16x16x32_bf16(kfl, qfh[ks], acc, 0, 0, 0);
        }
        S4[m] = acc;
      }

      // ---- mask + online softmax (row = lr, per-lane scalar) ----
      float sv[16]; unsigned okb = 0; float tmax = -INFINITY;
#pragma unroll
      for (int jj = 0; jj < 16; jj++) {
        const int bit = 16 * (jj >> 2) + 4 * g + (jj & 3);
        const bool ok = (mw >> bit) & 1ull;
        okb |= ((unsigned)ok) << jj;
        const float s = ok ? S4[jj >> 2][jj & 3] : -INFINITY;
        sv[jj] = s; tmax = fmaxf(tmax, s);
      }
      tmax = fmaxf(tmax, __shfl_xor(tmax, 16));
      tmax = fmaxf(tmax, __shfl_xor(tmax, 32));
      if (__any(tmax > mrun + 8.0f)) {  // T13 defer-max
        const float mnew = fmaxf(mrun, tmax);
        const float corr = (mnew == -INFINITY) ? 1.0f : __expf(mrun - mnew);
        lrun *= corr; mrun = mnew;
        float cr[4];
#pragma unroll
        for (int r = 0; r < 4; r++) cr[r] = __shfl(corr, 4 * g + r);
#pragma unroll
      for (int n = 0; n < 4; n++)
#pragma unroll
          for (int r = 0; r < 4; r++) Oacc[n][r] *= cr[r];
      }
      float pj[16]; float lsum = 0.f;
#pragma unroll
      for (int jj = 0; jj < 16; jj++) {
        const float e = __expf(sv[jj] - mrun);   // -inf-inf NaN killed below
        const float pv = ((okb >> jj) & 1u) ? e : 0.f;
        pj[jj] = pv; lsum += pv;
      }
      lsum += __shfl_xor(lsum, 16);
      lsum += __shfl_xor(lsum, 32);
      lrun += lsum;

      // ---- P split + write to per-wave LDS [qrow][key] ----
#pragma unroll
      for (int m = 0; m < 4; m++) {
        union { unsigned short us[4]; uint2 d; } h, l;
#pragma unroll
        for (int r = 0; r < 4; r++) {
          const float pv = pj[4 * m + r];
          const unsigned short hh = f2bf(pv);
          h.us[r] = hh; l.us[r] = f2bf(pv - bf2f(hh));
        }
        const unsigned byte =
            ((unsigned)(lr * 128 + (16 * m + 4 * g) * 2)) ^ swz;
        *(uint2*)((char*)Phs + 2048 * w + byte) = h.d;
        *(uint2*)((char*)Pls + 2048 * w + byte) = l.d;
      }
      asm volatile("s_waitcnt lgkmcnt(0)" ::: "memory");
      __builtin_amdgcn_sched_barrier(0);

      // ---- PV: O[qrow][d] += P . V ----
#pragma unroll
      for (int ks = 0; ks < 2; ks++) {
        const unsigned pb = ((unsigned)(lr * 128 + 64 * ks + 16 * g)) ^ swz;
        const s16x8 pfh = *(const s16x8*)((const char*)Phs + 2048 * w + pb);
        const s16x8 pfl = *(const s16x8*)((const char*)Pls + 2048 * w + pb);
#pragma unroll
        for (int n = 0; n < 4; n++) {
          const unsigned vb =
              ((unsigned)((16 * n + lr) * 128 + 64 * ks + 16 * g)) ^ swz;
          const s16x8 vfh = *(const s16x8*)((const char*)Vth + vb);
          const s16x8 vfl = *(const s16x8*)((const char*)Vtl + vb);
          Oacc[n] = __builtin_amdgcn_mfma_f32_16x16x32_bf16(pfh, vfh, Oacc[n], 0, 0, 0);
          Oacc[n] = __builtin_amdgcn_mfma_f32_16x16x32_bf16(pfh, vfl, Oacc[n], 0, 0, 0);
          Oacc[n] = __builtin_amdgcn_mfma_f32_16x16x32_bf16(pfl, vfh, Oacc[n], 0, 0, 0);
        }
      }
    }  // any mask bit

#pragma unroll
    for (int i = 0; i < 16; i++) { Kst[i] = Kst2[i]; Vst[i] = Vst2[i]; }
    mw = mwn;
  }

  // ---- finalize: O-row r lives at D-row 4g+r; its 1/l is on lane 4g+r ----
  const float linv = 1.0f / lrun;  // diagonal always unmasked -> lrun > 0
  float lr4[4];
#pragma unroll
  for (int r = 0; r < 4; r++) lr4[r] = __shfl(linv, 4 * g + r);
  const int orow0 = qt * 64 + w * 16;
  float* op = out + base;
#pragma unroll
  for (int n = 0; n < 4; n++)
#pragma unroll
    for (int r = 0; r < 4; r++)
      op[(size_t)(orow0 + 4 * g + r) * D_ + 16 * n + lr] = Oacc[n][r] * lr4[r];
}

extern "C" void kernel_launch(void* const* d_in, const int* in_sizes, int n_in,
                              void* d_out, int out_size, void* d_ws, size_t ws_size,
                              hipStream_t stream) {
  const float* q  = (const float*)d_in[0];
  const float* k  = (const float*)d_in[1];
  const float* v  = (const float*)d_in[2];
  const float* W1 = (const float*)d_in[3];
  const float* b1 = (const float*)d_in[4];
  const float* W2 = (const float*)d_in[5];
  const float* b2 = (const float*)d_in[6];
  float* out = (float*)d_out;

  // ws: probs [B*T*16] f32 (256 KB) | mask [B*T*16] u64 (512 KB)
  float* probs = (float*)d_ws;
  unsigned long long* mask =
      (unsigned long long*)((char*)d_ws + (size_t)B_ * T_ * NB * sizeof(float));

  router_kernel<<<512, 256, 0, stream>>>(k, W1, b1, W2, b2, probs);
  mask_v2<<<B_ * 16, 256, 0, stream>>>(probs, mask);
  attn_mfma<<<dim3(B_ * H_, T_ / 64), 256, 0, stream>>>(q, k, v, mask, out);
}

// Round 9
// 170.154 us; speedup vs baseline: 33.4715x; 1.3309x over previous
//
#include <hip/hip_runtime.h>
#include <hip/hip_bf16.h>

// SubQAttention: B=4, H=16, T=1024, D=64, N_BINS=16, ROUTER_HIDDEN=128
// Stage 1: router_v2 -> bucket_probs [B*T,16] f32 (ws). Register-blocked
//          (8 rows x 4 hu per thread), ds_read_b128 broadcast row fetches.
// Stage 2: mask_v3   -> bitmask [B*T,16] u64. 512 blocks, no LDS:
//          pj in regs, pi block-uniform (s_load).
// Stage 3: attn_mfma -> split-bf16 MFMA flash attention (3-term Markidis),
//          swapped QK^T, per-lane softmax, XOR-swizzled LDS.

#define B_ 4
#define H_ 16
#define T_ 1024
#define D_ 64
#define NB 16
#define RH 128

typedef __attribute__((ext_vector_type(8))) short s16x8;
typedef __attribute__((ext_vector_type(4))) float f32x4;

__device__ __forceinline__ unsigned short f2bf(float x) {  // HW RNE cast
  union { __hip_bfloat16 b; unsigned short u; } c;
  c.b = __hip_bfloat16(x);   // compiler emits v_cvt_pk_bf16_f32 for pairs
  return c.u;
}
__device__ __forceinline__ float bf2f(unsigned short h) {
  return __uint_as_float(((unsigned)h) << 16);
}

// ---------------- Stage 1: router v2 (8 rows/block, reg-blocked 8x4) -------
__global__ __launch_bounds__(256) void router_v2(
    const float* __restrict__ kin, const float* __restrict__ W1,
    const float* __restrict__ b1, const float* __restrict__ W2,
    const float* __restrict__ b2, float* __restrict__ probs) {
  __shared__ float rows[8][1024];     // 32 KB: 8 k_flat rows
  __shared__ float part[8][8][RH];    // 32 KB: [slice][row][hu]
  __shared__ float hid[8][RH + 4];    // padded, float4-aligned rows
  __shared__ float logits[8][NB];

  const int tid = threadIdx.x;
  const int bb = blockIdx.x;          // 512 blocks
  const int b = bb >> 7;
  const int t0 = (bb & 127) << 3;

  // stage k_flat rows via float4: k_flat[b,t,h*64+d] = k[b,h,t,d]
#pragma unroll
  for (int s = 0; s < 8; s++) {
    const int idx4 = tid + 256 * s;          // 0..2047
    const int r = idx4 >> 8, i = (idx4 & 255) * 4;
    const int h = i >> 6, d = i & 63;
    *(float4*)&rows[r][i] =
        *(const float4*)&kin[(((size_t)(b * H_) + h) * T_ + (t0 + r)) * D_ + d];
  }
  __syncthreads();

  // thread: hu0 = (tid&31)*4 (4 hidden units), slice = tid>>5 (128 k each)
  const int hu0 = (tid & 31) << 2;
  const int k0 = (tid >> 5) << 7;
  float acc[8][4];
#pragma unroll
  for (int r = 0; r < 8; r++)
#pragma unroll
    for (int c = 0; c < 4; c++) acc[r][c] = 0.0f;

  for (int kb = 0; kb < 128; kb += 4) {
    float4 rv[8];
#pragma unroll
    for (int r = 0; r < 8; r++) rv[r] = *(const float4*)&rows[r][k0 + kb];  // bcast
#pragma unroll
    for (int e = 0; e < 4; e++) {
      const float4 w = *(const float4*)&W1[(size_t)(k0 + kb + e) * RH + hu0];
#pragma unroll
      for (int r = 0; r < 8; r++) {
        const float rx = (&rv[r].x)[e];
        acc[r][0] += rx * w.x; acc[r][1] += rx * w.y;
        acc[r][2] += rx * w.z; acc[r][3] += rx * w.w;
      }
    }
  }
#pragma unroll
  for (int r = 0; r < 8; r++)
    *(float4*)&part[tid >> 5][r][hu0] =
        (float4){acc[r][0], acc[r][1], acc[r][2], acc[r][3]};
  __syncthreads();

  // reduce 8 slices -> tanh -> hid. thread owns 4 consecutive (r,hu) outputs.
  {
    const int p0 = tid * 4;
    const int r = p0 >> 7, hu = p0 & 127;
    float4 s = {0.f, 0.f, 0.f, 0.f};
#pragma unroll
    for (int sl = 0; sl < 8; sl++) {
      const float4 v = *(const float4*)&part[sl][r][hu];
      s.x += v.x; s.y += v.y; s.z += v.z; s.w += v.w;
    }
    const float4 bv = *(const float4*)&b1[hu];
    *(float4*)&hid[r][hu] = (float4){tanhf(s.x + bv.x), tanhf(s.y + bv.y),
                                     tanhf(s.z + bv.z), tanhf(s.w + bv.w)};
  }
  __syncthreads();

  if (tid < 128) {  // 8 rows x 16 bins
    const int r = tid >> 4, bin = tid & 15;
    float a = b2[bin];
#pragma unroll
    for (int jj = 0; jj < RH; jj++) a += hid[r][jj] * W2[jj * NB + bin];
    logits[r][bin] = a;
  }
  __syncthreads();

  if (tid < 8) {
    const int r = tid;
    float mx = -INFINITY;
#pragma unroll
    for (int bin = 0; bin < NB; bin++) mx = fmaxf(mx, logits[r][bin]);
    float e[NB];
    float s = 0.0f;
#pragma unroll
    for (int bin = 0; bin < NB; bin++) {
      e[bin] = expf(logits[r][bin] - mx);  // TEMPERATURE = 1
      s += e[bin];
    }
    const float inv = 1.0f / s;
    const size_t row = (size_t)(b * T_ + t0 + r) * NB;
#pragma unroll
    for (int bin = 0; bin < NB; bin++) probs[row + bin] = e[bin] * inv;
  }
}

// ---------------- Stage 2: bitmask v3 (512 blocks, no LDS) -----------------
__global__ __launch_bounds__(256) void mask_v3(
    const float* __restrict__ probs, unsigned long long* __restrict__ mask) {
  const int blk = blockIdx.x;          // 512
  const int b = blk >> 7, i0 = (blk & 127) << 3;  // 8 i-rows per block
  const int tid = threadIdx.x, w = tid >> 6;

  // pj rows in registers: j = jc*256 + tid
  float4 pjv[4][4];
#pragma unroll
  for (int jc = 0; jc < 4; jc++) {
    const float4* pjp =
        (const float4*)(probs + ((size_t)(b * T_ + jc * 256 + tid)) * NB);
#pragma unroll
    for (int qq = 0; qq < 4; qq++) pjv[jc][qq] = pjp[qq];
  }

  for (int ii = 0; ii < 8; ii++) {
    const int i = i0 + ii;
    const float4* pip = (const float4*)(probs + ((size_t)(b * T_ + i)) * NB);
    const float4 p0 = pip[0], p1 = pip[1], p2 = pip[2], p3 = pip[3];  // uniform
#pragma unroll
    for (int jc = 0; jc < 4; jc++) {
      const int j = jc * 256 + tid;
      float sim = p0.x * pjv[jc][0].x + p0.y * pjv[jc][0].y +
                  p0.z * pjv[jc][0].z + p0.w * pjv[jc][0].w;
      sim += p1.x * pjv[jc][1].x + p1.y * pjv[jc][1].y +
             p1.z * pjv[jc][1].z + p1.w * pjv[jc][1].w;
      sim += p2.x * pjv[jc][2].x + p2.y * pjv[jc][2].y +
             p2.z * pjv[jc][2].z + p2.w * pjv[jc][2].w;
      sim += p3.x * pjv[jc][3].x + p3.y * pjv[jc][3].y +
             p3.z * pjv[jc][3].z + p3.w * pjv[jc][3].w;
      const unsigned long long bal = __ballot((j <= i) && (sim > 0.05f));
      if ((tid & 63) == 0)
        mask[((size_t)(b * T_ + i) << 4) + jc * 4 + w] = bal;
    }
  }
}

// ---------------- Stage 3: split-bf16 MFMA flash attention -----------------
// Block = 4 waves, (bh, q-tile of 64). Wave w owns q-rows w*16..+15.
// Swapped QK^T: S^T = K_tile . Q^T -> lane's softmax row = lane&15.
// 3-term split everywhere keeps fp32 accuracy.
__global__ __launch_bounds__(256, 2) void attn_mfma(
    const float* __restrict__ q, const float* __restrict__ k,
    const float* __restrict__ v, const unsigned long long* __restrict__ mask,
    float* __restrict__ out) {
  __shared__ unsigned short Kh[64 * 64], Kl[64 * 64];    // [key][d]  swz
  __shared__ unsigned short Vth[64 * 64], Vtl[64 * 64];  // [d][key]  swz
  __shared__ unsigned short Phs[4][1024], Pls[4][1024];  // per-wave [qrow][key] swz

  const int bh = blockIdx.x, qt = blockIdx.y;
  const int b = bh >> 4;
  const int tid = threadIdx.x, w = tid >> 6, lane = tid & 63;
  const int lr = lane & 15;   // qrow-local / d-local (MFMA 16-field)
  const int g = lane >> 4;    // k-group (MFMA 4-field)
  const size_t base = (size_t)bh * (T_ * D_);
  const int qrow_g = qt * 64 + w * 16 + lr;
  const unsigned swz = ((unsigned)(lr & 7)) << 4;

  // ---- Q fragments (pre-scaled by D^-0.5 = 0.125, split hi/lo) ----
  s16x8 qfh[2], qfl[2];
  {
    const float* qp = q + base + (size_t)qrow_g * D_;
#pragma unroll
    for (int ks = 0; ks < 2; ks++) {
      union { unsigned short us[8]; s16x8 v; } h, l;
#pragma unroll
      for (int e2 = 0; e2 < 2; e2++) {
        const float4 f = *(const float4*)(qp + 32 * ks + 8 * g + 4 * e2);
#pragma unroll
        for (int e = 0; e < 4; e++) {
          const float x = (&f.x)[e] * 0.125f;
          const unsigned short hh = f2bf(x);
          h.us[4 * e2 + e] = hh;
          l.us[4 * e2 + e] = f2bf(x - bf2f(hh));
        }
      }
      qfh[ks] = h.v; qfl[ks] = l.v;
    }
  }

  f32x4 Oacc[4];
#pragma unroll
  for (int n = 0; n < 4; n++) Oacc[n] = (f32x4){0.f, 0.f, 0.f, 0.f};
  float mrun = -INFINITY, lrun = 0.f;

  const unsigned long long* mrow = mask + ((size_t)(b * T_ + qrow_g) << 4);
  const int dv = tid & 63, k0v = (tid >> 6) * 16;  // V-stage mapping

  // ---- prologue: load tile 0 into regs ----
  float Kst[16], Vst[16], Kst2[16], Vst2[16];
  {
    const float4* kp4 = (const float4*)(k + base);
    const float* vp = v + base;
#pragma unroll
    for (int i = 0; i < 4; i++) {
      const float4 f = kp4[tid + 256 * i];
      Kst[4 * i + 0] = f.x; Kst[4 * i + 1] = f.y;
      Kst[4 * i + 2] = f.z; Kst[4 * i + 3] = f.w;
    }
#pragma unroll
    for (int j = 0; j < 16; j++) Vst[j] = vp[(size_t)(k0v + j) * D_ + dv];
  }
  unsigned long long mw = mrow[0];

  for (int kt = 0; kt <= qt; kt++) {
    __syncthreads();  // previous tile's LDS reads done
    // ---- write stage: cvt + split + swizzled LDS writes ----
#pragma unroll
    for (int i = 0; i < 4; i++) {  // K: [key][d], b64 per float4
      const int flat4 = tid + 256 * i, key = flat4 >> 4, dq = flat4 & 15;
      union { unsigned short us[4]; uint2 d; } h, l;
#pragma unroll
      for (int e = 0; e < 4; e++) {
        const float x = Kst[4 * i + e];
        const unsigned short hh = f2bf(x);
        h.us[e] = hh; l.us[e] = f2bf(x - bf2f(hh));
      }
      const unsigned byte = (unsigned)(key * 128 + dq * 8) ^ (((unsigned)(key & 7)) << 4);
      *(uint2*)((char*)Kh + byte) = h.d;
      *(uint2*)((char*)Kl + byte) = l.d;
    }
#pragma unroll
    for (int i = 0; i < 2; i++) {  // V transposed: [d][key], b128 per 8 keys
      union { unsigned short us[8]; uint4 q; } h, l;
#pragma unroll
      for (int j = 0; j < 8; j++) {
        const float x = Vst[8 * i + j];
        const unsigned short hh = f2bf(x);
        h.us[j] = hh; l.us[j] = f2bf(x - bf2f(hh));
      }
      const unsigned byte =
          (unsigned)(dv * 128 + (k0v + 8 * i) * 2) ^ (((unsigned)(dv & 7)) << 4);
      *(uint4*)((char*)Vth + byte) = h.q;
      *(uint4*)((char*)Vtl + byte) = l.q;
    }
    __syncthreads();  // staged tile visible

    // ---- prefetch next tile (hidden under compute) ----
    const int ktn = (kt < qt) ? kt + 1 : qt;
    {
      const float4* kp4 = (const float4*)(k + base + (size_t)(ktn * 64) * D_);
      const float* vp = v + base + (size_t)(ktn * 64) * D_;
#pragma unroll
      for (int i = 0; i < 4; i++) {
        const float4 f = kp4[tid + 256 * i];
        Kst2[4 * i + 0] = f.x; Kst2[4 * i + 1] = f.y;
        Kst2[4 * i + 2] = f.z; Kst2[4 * i + 3] = f.w;
      }
#pragma unroll
      for (int j = 0; j < 16; j++) Vst2[j] = vp[(size_t)(k0v + j) * D_ + dv];
    }
    const unsigned long long mwn = mrow[ktn];

    if (__any(mw != 0ull)) {
      // ---- QK^T (swapped): S4[m][r] = S[key=16m+4g+r][qrow=lr], pre-scaled
      f32x4 S4[4];
#pragma unroll
      for (int m = 0; m < 4; m++) {
        f32x4 acc = (f32x4){0.f, 0.f, 0.f, 0.f};
#pragma unroll
        for (int ks = 0; ks < 2; ks++) {
          const unsigned byte =
              ((unsigned)((16 * m + lr) * 128 + 64 * ks + 16 * g)) ^ swz;
          const s16x8 kfh = *(const s16x8*)((const char*)Kh + byte);
          const s16x8 kfl = *(const s16x8*)((const char*)Kl + byte);
          acc = __builtin_amdgcn_mfma_f32_16x16x32_bf16(kfh, qfh[ks], acc, 0, 0, 0);
          acc = __builtin_amdgcn_mfma_f32_16x16x32_bf16(kfh, qfl[ks], acc, 0, 0, 0);
          acc = __builtin_amdgcn_mfma_f32_16x16x32_bf16(kfl, qfh[ks], acc, 0, 0, 0);
        }
        S4[m] = acc;
      }

      // ---- mask + online softmax (row = lr, per-lane scalar) ----
      float sv[16]; unsigned okb = 0; float tmax = -INFINITY;
#pragma unroll
      for (int jj = 0; jj < 16; jj++) {
        const int bit = 16 * (jj >> 2) + 4 * g + (jj & 3);
        const bool ok = (mw >> bit) & 1ull;
        okb |= ((unsigned)ok) << jj;
        const float s = ok ? S4[jj >> 2][jj & 3] : -INFINITY;
        sv[jj] = s; tmax = fmaxf(tmax, s);
      }
      tmax = fmaxf(tmax, __shfl_xor(tmax, 16));
      tmax = fmaxf(tmax, __shfl_xor(tmax, 32));
      if (__any(tmax > mrun + 8.0f)) {  // T13 defer-max
        const float mnew = fmaxf(mrun, tmax);
        const float corr = (mnew == -INFINITY) ? 1.0f : __expf(mrun - mnew);
        lrun *= corr; mrun = mnew;
        float cr[4];
#pragma unroll
        for (int r = 0; r < 4; r++) cr[r] = __shfl(corr, 4 * g + r);
#pragma unroll
        for (int n = 0; n < 4; n++)
#pragma unroll
          for (int r = 0; r < 4; r++) Oacc[n][r] *= cr[r];
      }
      float pj[16]; float lsum = 0.f;
#pragma unroll
      for (int jj = 0; jj < 16; jj++) {
        const float e = __expf(sv[jj] - mrun);
        const float pv = ((okb >> jj) & 1u) ? e : 0.f;
        pj[jj] = pv; lsum += pv;
      }
      lsum += __shfl_xor(lsum, 16);
      lsum += __shfl_xor(lsum, 32);
      lrun += lsum;

      // ---- P split + write to per-wave LDS [qrow][key] ----
#pragma unroll
      for (int m = 0; m < 4; m++) {
        union { unsigned short us[4]; uint2 d; } h, l;
#pragma unroll
        for (int r = 0; r < 4; r++) {
          const float pv = pj[4 * m + r];
          const unsigned short hh = f2bf(pv);
          h.us[r] = hh; l.us[r] = f2bf(pv - bf2f(hh));
        }
        const unsigned byte =
            ((unsigned)(lr * 128 + (16 * m + 4 * g) * 2)) ^ swz;
        *(uint2*)((char*)Phs + 2048 * w + byte) = h.d;
        *(uint2*)((char*)Pls + 2048 * w + byte) = l.d;
      }
      asm volatile("s_waitcnt lgkmcnt(0)" ::: "memory");
      __builtin_amdgcn_sched_barrier(0);

      // ---- PV: O[qrow][d] += P . V ----
#pragma unroll
      for (int ks = 0; ks < 2; ks++) {
        const unsigned pb = ((unsigned)(lr * 128 + 64 * ks + 16 * g)) ^ swz;
        const s16x8 pfh = *(const s16x8*)((const char*)Phs + 2048 * w + pb);
        const s16x8 pfl = *(const s16x8*)((const char*)Pls + 2048 * w + pb);
#pragma unroll
        for (int n = 0; n < 4; n++) {
          const unsigned vb =
              ((unsigned)((16 * n + lr) * 128 + 64 * ks + 16 * g)) ^ swz;
          const s16x8 vfh = *(const s16x8*)((const char*)Vth + vb);
          const s16x8 vfl = *(const s16x8*)((const char*)Vtl + vb);
          Oacc[n] = __builtin_amdgcn_mfma_f32_16x16x32_bf16(pfh, vfh, Oacc[n], 0, 0, 0);
          Oacc[n] = __builtin_amdgcn_mfma_f32_16x16x32_bf16(pfh, vfl, Oacc[n], 0, 0, 0);
          Oacc[n] = __builtin_amdgcn_mfma_f32_16x16x32_bf16(pfl, vfh, Oacc[n], 0, 0, 0);
        }
      }
    }  // any mask bit

#pragma unroll
    for (int i = 0; i < 16; i++) { Kst[i] = Kst2[i]; Vst[i] = Vst2[i]; }
    mw = mwn;
  }

  // ---- finalize: O-row r lives at D-row 4g+r; its 1/l is on lane 4g+r ----
  const float linv = 1.0f / lrun;  // diagonal always unmasked -> lrun > 0
  float lr4[4];
#pragma unroll
  for (int r = 0; r < 4; r++) lr4[r] = __shfl(linv, 4 * g + r);
  const int orow0 = qt * 64 + w * 16;
  float* op = out + base;
#pragma unroll
  for (int n = 0; n < 4; n++)
#pragma unroll
    for (int r = 0; r < 4; r++)
      op[(size_t)(orow0 + 4 * g + r) * D_ + 16 * n + lr] = Oacc[n][r] * lr4[r];
}

extern "C" void kernel_launch(void* const* d_in, const int* in_sizes, int n_in,
                              void* d_out, int out_size, void* d_ws, size_t ws_size,
                              hipStream_t stream) {
  const float* q  = (const float*)d_in[0];
  const float* k  = (const float*)d_in[1];
  const float* v  = (const float*)d_in[2];
  const float* W1 = (const float*)d_in[3];
  const float* b1 = (const float*)d_in[4];
  const float* W2 = (const float*)d_in[5];
  const float* b2 = (const float*)d_in[6];
  float* out = (float*)d_out;

  // ws: probs [B*T*16] f32 (256 KB) | mask [B*T*16] u64 (512 KB)
  float* probs = (float*)d_ws;
  unsigned long long* mask =
      (unsigned long long*)((char*)d_ws + (size_t)B_ * T_ * NB * sizeof(float));

  router_v2<<<512, 256, 0, stream>>>(k, W1, b1, W2, b2, probs);
  mask_v3<<<512, 256, 0, stream>>>(probs, mask);
  attn_mfma<<<dim3(B_ * H_, T_ / 64), 256, 0, stream>>>(q, k, v, mask, out);
}